// Round 2
// baseline (686.927 us; speedup 1.0000x reference)
//
#include <hip/hip_runtime.h>
#include <hip/hip_cooperative_groups.h>

namespace cg = cooperative_groups;

#define CDIM 768
#define SDIM 4096
#define SV (SDIM / 4) // row length in float4

typedef float nfloat4 __attribute__((ext_vector_type(4))); // native vec for nontemporal builtin

// one wave computes out[b,c] = bias[c] + sum_k X[b,k]*W[c,k]; waves stride over 16*768 outputs
__device__ __forceinline__ void gemm16(
    const float* __restrict__ X, const float* __restrict__ W,
    const float* __restrict__ bias, float* __restrict__ out,
    int K, int wave, int nwaves, int lane)
{
    for (int idx = wave; idx < 16 * CDIM; idx += nwaves) {
        int b = idx / CDIM;
        int c = idx - b * CDIM;
        const float* x = X + (size_t)b * K;
        const float* w = W + (size_t)c * K;
        float acc = 0.f;
        for (int k = lane * 4; k < K; k += 256) {
            float4 xv = *(const float4*)(x + k);
            float4 wv = *(const float4*)(w + k);
            acc += xv.x * wv.x + xv.y * wv.y + xv.z * wv.z + xv.w * wv.w;
        }
#pragma unroll
        for (int m = 32; m; m >>= 1) acc += __shfl_xor(acc, m, 64);
        if (lane == 0) out[idx] = acc + bias[c];
    }
}

// Entire conditioning->proj chain in one cooperative kernel: 4 tiny GEMMs
// separated by grid-wide syncs instead of 4 dependent kernel launches.
__global__ __launch_bounds__(256) void gemm_chain_coop(
    const float* __restrict__ conditioning,
    const float* __restrict__ w_cond,  const float* __restrict__ b_cond,
    const float* __restrict__ wv,      const float* __restrict__ bv,
    const float* __restrict__ attn_w,  const float* __restrict__ attn_b,
    const float* __restrict__ w_out,   const float* __restrict__ b_out,
    float* __restrict__ cond, float* __restrict__ v,
    float* __restrict__ attn, float* __restrict__ proj)
{
    cg::grid_group grid = cg::this_grid();
    const int nwaves = (gridDim.x * blockDim.x) >> 6;
    const int wave   = (blockIdx.x * blockDim.x + threadIdx.x) >> 6;
    const int lane   = threadIdx.x & 63;

    gemm16(conditioning, w_cond, b_cond, cond, 1024, wave, nwaves, lane);
    __threadfence();
    grid.sync();
    gemm16(cond, wv, bv, v, CDIM, wave, nwaves, lane);
    __threadfence();
    grid.sync();
    gemm16(v, attn_w, attn_b, attn, CDIM, wave, nwaves, lane);
    __threadfence();
    grid.sync();
    gemm16(attn, w_out, b_out, proj, CDIM, wave, nwaves, lane);
}

// Single-read fused add+LN (unchanged from round 1, 131 us measured).
__global__ __launch_bounds__(512) void fused_add_ln_1pass(
    const float* __restrict__ sp, const float* __restrict__ proj,
    const float* __restrict__ gamma, const float* __restrict__ beta,
    float* __restrict__ out)
{
    __shared__ float s_proj[CDIM], s_gamma[CDIM], s_beta[CDIM];
    __shared__ float4 red_s[64][8];
    __shared__ float4 red_q[64][8];
    __shared__ float4 red2_s[8][8];
    __shared__ float4 red2_q[8][8];
    __shared__ float4 s_mu[8];
    __shared__ float4 s_rs[8];

    const int b  = blockIdx.y;
    const int s0 = blockIdx.x * 32;
    const int t  = threadIdx.x;
    for (int i = t; i < CDIM; i += 512) {
        s_proj[i]  = proj[b * CDIM + i];
        s_gamma[i] = gamma[i];
        s_beta[i]  = beta[i];
    }
    __syncthreads();

    const int si = t & 7;
    const int cg2 = t >> 3;
    const int c0 = cg2 * (CDIM / 64);      // 12 c's per thread

    const float4* spv  = (const float4*)(sp  + (size_t)b * CDIM * SDIM + s0) + (size_t)c0 * SV + si;
    nfloat4*      outv = (nfloat4*)     (out + (size_t)b * CDIM * SDIM + s0) + (size_t)c0 * SV + si;

    float4 x[12];
    float sx = 0, sy = 0, sz = 0, sw = 0;
    float qx = 0, qy = 0, qz = 0, qw = 0;
#pragma unroll
    for (int j = 0; j < 12; ++j) {
        float4 v = spv[(size_t)j * SV];
        float  p = s_proj[c0 + j];
        v.x += p; v.y += p; v.z += p; v.w += p;
        x[j] = v;
        sx += v.x; sy += v.y; sz += v.z; sw += v.w;
        qx += v.x * v.x; qy += v.y * v.y; qz += v.z * v.z; qw += v.w * v.w;
    }
    red_s[cg2][si] = make_float4(sx, sy, sz, sw);
    red_q[cg2][si] = make_float4(qx, qy, qz, qw);
    __syncthreads();

    if (t < 64) {
        const int si2 = t & 7;
        const int h   = t >> 3;
        float4 S = make_float4(0, 0, 0, 0), Q = make_float4(0, 0, 0, 0);
#pragma unroll
        for (int g = h * 8; g < h * 8 + 8; ++g) {
            float4 a = red_s[g][si2], q = red_q[g][si2];
            S.x += a.x; S.y += a.y; S.z += a.z; S.w += a.w;
            Q.x += q.x; Q.y += q.y; Q.z += q.z; Q.w += q.w;
        }
        red2_s[h][si2] = S;
        red2_q[h][si2] = Q;
    }
    __syncthreads();

    if (t < 8) {
        float4 S = make_float4(0, 0, 0, 0), Q = make_float4(0, 0, 0, 0);
#pragma unroll
        for (int h = 0; h < 8; ++h) {
            float4 a = red2_s[h][t], q = red2_q[h][t];
            S.x += a.x; S.y += a.y; S.z += a.z; S.w += a.w;
            Q.x += q.x; Q.y += q.y; Q.z += q.z; Q.w += q.w;
        }
        const float inv = 1.f / CDIM;
        float4 mu = make_float4(S.x * inv, S.y * inv, S.z * inv, S.w * inv);
        float4 rs;
        rs.x = rsqrtf(Q.x * inv - mu.x * mu.x + 1e-5f);
        rs.y = rsqrtf(Q.y * inv - mu.y * mu.y + 1e-5f);
        rs.z = rsqrtf(Q.z * inv - mu.z * mu.z + 1e-5f);
        rs.w = rsqrtf(Q.w * inv - mu.w * mu.w + 1e-5f);
        s_mu[t] = mu;
        s_rs[t] = rs;
    }
    __syncthreads();

    const float4 mu = s_mu[si];
    const float4 rs = s_rs[si];
#pragma unroll
    for (int j = 0; j < 12; ++j) {
        float g  = s_gamma[c0 + j];
        float be = s_beta[c0 + j];
        nfloat4 y;
        y.x = (x[j].x - mu.x) * rs.x * g + be;
        y.y = (x[j].y - mu.y) * rs.y * g + be;
        y.z = (x[j].z - mu.z) * rs.z * g + be;
        y.w = (x[j].w - mu.w) * rs.w * g + be;
        __builtin_nontemporal_store(y, &outv[(size_t)j * SV]);
    }
}

extern "C" void kernel_launch(void* const* d_in, const int* in_sizes, int n_in,
                              void* d_out, int out_size, void* d_ws, size_t ws_size,
                              hipStream_t stream) {
    const float* sp           = (const float*)d_in[0];
    const float* conditioning = (const float*)d_in[1];
    const float* w_cond       = (const float*)d_in[2];
    const float* b_cond       = (const float*)d_in[3];
    const float* in_proj_w    = (const float*)d_in[4];
    const float* in_proj_b    = (const float*)d_in[5];
    const float* attn_out_w   = (const float*)d_in[6];
    const float* attn_out_b   = (const float*)d_in[7];
    const float* w_out        = (const float*)d_in[8];
    const float* b_out        = (const float*)d_in[9];
    const float* ln_gamma     = (const float*)d_in[10];
    const float* ln_beta      = (const float*)d_in[11];
    float* out = (float*)d_out;
    float* ws  = (float*)d_ws;

    float* cond = ws;            // 16*768
    float* v    = ws + 12288;    // 16*768
    float* attn = ws + 24576;    // 16*768
    float* proj = ws + 36864;    // 16*768

    const float* wv = in_proj_w + 2 * CDIM * CDIM;
    const float* bv = in_proj_b + 2 * CDIM;

    void* args[] = {
        (void*)&conditioning,
        (void*)&w_cond, (void*)&b_cond,
        (void*)&wv,     (void*)&bv,
        (void*)&attn_out_w, (void*)&attn_out_b,
        (void*)&w_out,  (void*)&b_out,
        (void*)&cond, (void*)&v, (void*)&attn, (void*)&proj,
    };
    // 512 blocks x 256 threads: 2 blocks/CU, trivially co-resident (no LDS, low VGPR)
    hipLaunchCooperativeKernel((const void*)gemm_chain_coop,
                               dim3(512), dim3(256), args, 0, stream);

    dim3 grid(SDIM / 32, 16);
    fused_add_ln_1pass<<<grid, 512, 0, stream>>>(sp, proj, ln_gamma, ln_beta, out);
}

// Round 3
// 424.945 us; speedup vs baseline: 1.6165x; 1.6165x over previous
//
#include <hip/hip_runtime.h>

#define CDIM 768
#define SDIM 4096
#define SV (SDIM / 4) // row length in float4

typedef float nfloat4 __attribute__((ext_vector_type(4))); // native vec for nontemporal builtin

// out[b,c] = bias[c] + sum_k X[b,k] * W[c,k]   (one wave per output element)
__global__ __launch_bounds__(256) void small_gemm_kernel(
    const float* __restrict__ X, const float* __restrict__ W,
    const float* __restrict__ bias, float* __restrict__ out,
    int Cn, int K)
{
    int gid  = blockIdx.x * blockDim.x + threadIdx.x;
    int wid  = gid >> 6;
    int lane = threadIdx.x & 63;
    int total = 16 * Cn;
    if (wid >= total) return;
    int b = wid / Cn;
    int c = wid - b * Cn;
    const float* x = X + (size_t)b * K;
    const float* w = W + (size_t)c * K;
    float acc = 0.f;
    for (int k = lane * 4; k < K; k += 256) {
        float4 xv = *(const float4*)(x + k);
        float4 wv = *(const float4*)(w + k);
        acc += xv.x * wv.x + xv.y * wv.y + xv.z * wv.z + xv.w * wv.w;
    }
#pragma unroll
    for (int m = 32; m; m >>= 1) acc += __shfl_xor(acc, m, 64);
    if (lane == 0) out[wid] = acc + bias[c];
}

// Single-read fused add+LN, v2.
// Block = 256 threads, tile = 16 s-positions (4 float4 columns) x all 768 c.
// Thread t: si = t&3, cg = t>>2 (0..63), 12 c's per thread, x kept in registers.
// Reduction: in-wave __shfl_xor tree over the 16 lanes sharing si (masks
// 4/8/16/32) -> 4x4 LDS exchange -> every thread computes mu/rs redundantly.
// No serial reduce stages, 2 barriers, ~10KB LDS, 4-wave blocks -> ~6-8
// blocks/CU resident (was 4 with 512-thread blocks + 3 barriers + serial
// stages at 33% occupancy).
__global__ __launch_bounds__(256) void fused_add_ln_v2(
    const float* __restrict__ sp, const float* __restrict__ proj,
    const float* __restrict__ gamma, const float* __restrict__ beta,
    float* __restrict__ out)
{
    __shared__ float s_proj[CDIM], s_gamma[CDIM], s_beta[CDIM];
    __shared__ float4 red_s[4][4];
    __shared__ float4 red_q[4][4];

    const int b  = blockIdx.y;
    const int s0 = blockIdx.x * 16;
    const int t  = threadIdx.x;
    for (int i = t; i < CDIM; i += 256) {
        s_proj[i]  = proj[b * CDIM + i];
        s_gamma[i] = gamma[i];
        s_beta[i]  = beta[i];
    }
    __syncthreads();

    const int si = t & 3;
    const int cg = t >> 2;
    const int c0 = cg * (CDIM / 64);       // 12 c's per thread

    const float4* spv  = (const float4*)(sp  + (size_t)b * CDIM * SDIM + s0) + (size_t)c0 * SV + si;
    nfloat4*      outv = (nfloat4*)     (out + (size_t)b * CDIM * SDIM + s0) + (size_t)c0 * SV + si;

    float4 x[12];
    float4 S = make_float4(0, 0, 0, 0);
    float4 Q = make_float4(0, 0, 0, 0);
#pragma unroll
    for (int j = 0; j < 12; ++j) {
        float4 v = spv[(size_t)j * SV];
        float  p = s_proj[c0 + j];
        v.x += p; v.y += p; v.z += p; v.w += p;
        x[j] = v;
        S.x += v.x; S.y += v.y; S.z += v.z; S.w += v.w;
        Q.x += v.x * v.x; Q.y += v.y * v.y; Q.z += v.z * v.z; Q.w += v.w * v.w;
    }

    // reduce across the 16 lanes of this wave sharing si
#pragma unroll
    for (int m = 4; m <= 32; m <<= 1) {
        S.x += __shfl_xor(S.x, m, 64); S.y += __shfl_xor(S.y, m, 64);
        S.z += __shfl_xor(S.z, m, 64); S.w += __shfl_xor(S.w, m, 64);
        Q.x += __shfl_xor(Q.x, m, 64); Q.y += __shfl_xor(Q.y, m, 64);
        Q.z += __shfl_xor(Q.z, m, 64); Q.w += __shfl_xor(Q.w, m, 64);
    }
    const int wave = t >> 6;
    const int lane = t & 63;
    if (lane < 4) {
        red_s[wave][lane] = S;
        red_q[wave][lane] = Q;
    }
    __syncthreads();

    // final 4-way cross-wave sum; every thread computes mu/rs (broadcast reads)
    float4 Sa = make_float4(0, 0, 0, 0), Qa = make_float4(0, 0, 0, 0);
#pragma unroll
    for (int g = 0; g < 4; ++g) {
        float4 a = red_s[g][si], q = red_q[g][si];
        Sa.x += a.x; Sa.y += a.y; Sa.z += a.z; Sa.w += a.w;
        Qa.x += q.x; Qa.y += q.y; Qa.z += q.z; Qa.w += q.w;
    }
    const float inv = 1.f / CDIM;
    float4 mu = make_float4(Sa.x * inv, Sa.y * inv, Sa.z * inv, Sa.w * inv);
    float4 rs;
    rs.x = rsqrtf(Qa.x * inv - mu.x * mu.x + 1e-5f);
    rs.y = rsqrtf(Qa.y * inv - mu.y * mu.y + 1e-5f);
    rs.z = rsqrtf(Qa.z * inv - mu.z * mu.z + 1e-5f);
    rs.w = rsqrtf(Qa.w * inv - mu.w * mu.w + 1e-5f);

#pragma unroll
    for (int j = 0; j < 12; ++j) {
        float g  = s_gamma[c0 + j];
        float be = s_beta[c0 + j];
        nfloat4 y;
        y.x = (x[j].x - mu.x) * rs.x * g + be;
        y.y = (x[j].y - mu.y) * rs.y * g + be;
        y.z = (x[j].z - mu.z) * rs.z * g + be;
        y.w = (x[j].w - mu.w) * rs.w * g + be;
        __builtin_nontemporal_store(y, &outv[(size_t)j * SV]);
    }
}

extern "C" void kernel_launch(void* const* d_in, const int* in_sizes, int n_in,
                              void* d_out, int out_size, void* d_ws, size_t ws_size,
                              hipStream_t stream) {
    const float* sp           = (const float*)d_in[0];
    const float* conditioning = (const float*)d_in[1];
    const float* w_cond       = (const float*)d_in[2];
    const float* b_cond       = (const float*)d_in[3];
    const float* in_proj_w    = (const float*)d_in[4];
    const float* in_proj_b    = (const float*)d_in[5];
    const float* attn_out_w   = (const float*)d_in[6];
    const float* attn_out_b   = (const float*)d_in[7];
    const float* w_out        = (const float*)d_in[8];
    const float* b_out        = (const float*)d_in[9];
    const float* ln_gamma     = (const float*)d_in[10];
    const float* ln_beta      = (const float*)d_in[11];
    float* out = (float*)d_out;
    float* ws  = (float*)d_ws;

    float* cond = ws;            // 16*768
    float* v    = ws + 12288;    // 16*768
    float* attn = ws + 24576;    // 16*768
    float* proj = ws + 36864;    // 16*768

    const int gemm_blocks = (16 * CDIM) / 4; // 4 waves/block, one wave per output
    small_gemm_kernel<<<gemm_blocks, 256, 0, stream>>>(
        conditioning, w_cond, b_cond, cond, CDIM, 1024);
    small_gemm_kernel<<<gemm_blocks, 256, 0, stream>>>(
        cond, in_proj_w + 2 * CDIM * CDIM, in_proj_b + 2 * CDIM, v, CDIM, CDIM);
    small_gemm_kernel<<<gemm_blocks, 256, 0, stream>>>(
        v, attn_out_w, attn_out_b, attn, CDIM, CDIM);
    small_gemm_kernel<<<gemm_blocks, 256, 0, stream>>>(
        attn, w_out, b_out, proj, CDIM, CDIM);

    dim3 grid(SDIM / 16, 16);
    fused_add_ln_v2<<<grid, 256, 0, stream>>>(sp, proj, ln_gamma, ln_beta, out);
}

// Round 4
// 411.020 us; speedup vs baseline: 1.6713x; 1.0339x over previous
//
#include <hip/hip_runtime.h>

#define CDIM 768
#define SDIM 4096

typedef float nfloat4 __attribute__((ext_vector_type(4))); // native vec for nontemporal builtin

// out[b,c] = bias[c] + sum_k X[b,k] * W[c,k]   (one wave per output element)
__global__ __launch_bounds__(256) void small_gemm_kernel(
    const float* __restrict__ X, const float* __restrict__ W,
    const float* __restrict__ bias, float* __restrict__ out,
    int Cn, int K)
{
    int gid  = blockIdx.x * blockDim.x + threadIdx.x;
    int wid  = gid >> 6;
    int lane = threadIdx.x & 63;
    int total = 16 * Cn;
    if (wid >= total) return;
    int b = wid / Cn;
    int c = wid - b * Cn;
    const float* x = X + (size_t)b * K;
    const float* w = W + (size_t)c * K;
    float acc = 0.f;
    for (int k = lane * 4; k < K; k += 256) {
        float4 xv = *(const float4*)(x + k);
        float4 wv = *(const float4*)(w + k);
        acc += xv.x * wv.x + xv.y * wv.y + xv.z * wv.z + xv.w * wv.w;
    }
#pragma unroll
    for (int m = 32; m; m >>= 1) acc += __shfl_xor(acc, m, 64);
    if (lane == 0) out[wid] = acc + bias[c];
}

// Pass 1: A[b,s] = sum_c (sp+p), B[b,s] = sum_c (sp+p)^2, fully contiguous reads.
// Block = (b, 128-s span), 256 threads = 4 waves; wave w owns c-range [w*192, w*192+192).
// Each lane owns 2 consecutive s (float2): per-row wave-load = 512B contiguous.
// No cross-lane reduction at all; 4-wave combine via tiny LDS exchange.
__global__ __launch_bounds__(256) void ln_stats(
    const float* __restrict__ sp, const float* __restrict__ proj,
    float* __restrict__ Aout, float* __restrict__ Bout)
{
    __shared__ float s_proj[CDIM];
    __shared__ float2 redA[4][64];
    __shared__ float2 redB[4][64];
    const int b  = blockIdx.y;
    const int s0 = blockIdx.x * 128;
    const int t  = threadIdx.x;
    for (int i = t; i < CDIM; i += 256) s_proj[i] = proj[b * CDIM + i];
    __syncthreads();

    const int lane = t & 63;
    const int wave = t >> 6;
    const float2* base = (const float2*)(sp + (size_t)b * CDIM * SDIM + s0) + lane;

    float2 A = make_float2(0.f, 0.f), B = make_float2(0.f, 0.f);
    const int cbeg = wave * (CDIM / 4);
    for (int c = cbeg; c < cbeg + CDIM / 4; c += 8) {
        float2 v[8];
#pragma unroll
        for (int k = 0; k < 8; ++k) v[k] = base[(size_t)(c + k) * (SDIM / 2)];
#pragma unroll
        for (int k = 0; k < 8; ++k) {
            float p  = s_proj[c + k];
            float ax = v[k].x + p, ay = v[k].y + p;
            A.x += ax;      A.y += ay;
            B.x += ax * ax; B.y += ay * ay;
        }
    }
    redA[wave][lane] = A;
    redB[wave][lane] = B;
    __syncthreads();

    if (t < 64) {
        float2 a = redA[0][t], bb = redB[0][t];
#pragma unroll
        for (int w = 1; w < 4; ++w) {
            a.x  += redA[w][t].x;  a.y  += redA[w][t].y;
            bb.x += redB[w][t].x;  bb.y += redB[w][t].y;
        }
        ((float2*)(Aout + (size_t)b * SDIM + s0))[t] = a;
        ((float2*)(Bout + (size_t)b * SDIM + s0))[t] = bb;
    }
}

// Pass 2: normalize + write, fully contiguous. Block = (b, 256-s span, 1/4 of c).
// Each lane owns 4 consecutive s; mu/rs live in registers (float4 per lane).
// Per row: 1KB contiguous wave-load of sp, FMA, 1KB contiguous nontemporal store.
__global__ __launch_bounds__(256) void ln_norm(
    const float* __restrict__ sp, const float* __restrict__ proj,
    const float* __restrict__ Ain, const float* __restrict__ Bin,
    const float* __restrict__ gamma, const float* __restrict__ beta,
    float* __restrict__ out)
{
    __shared__ float s_p[CDIM / 4], s_g[CDIM / 4], s_b[CDIM / 4];
    const int b      = blockIdx.y;
    const int s0     = blockIdx.x * 256;
    const int c_base = blockIdx.z * (CDIM / 4);   // 192 c's per block
    const int t      = threadIdx.x;
    if (t < CDIM / 4) {
        s_p[t] = proj[b * CDIM + c_base + t];
        s_g[t] = gamma[c_base + t];
        s_b[t] = beta[c_base + t];
    }
    __syncthreads();

    const int lane = t & 63;
    const int wave = t >> 6;

    float4 A  = ((const float4*)(Ain + (size_t)b * SDIM + s0))[lane];
    float4 Bv = ((const float4*)(Bin + (size_t)b * SDIM + s0))[lane];
    const float inv = 1.f / CDIM;
    float4 mu, rs;
    mu.x = A.x * inv; mu.y = A.y * inv; mu.z = A.z * inv; mu.w = A.w * inv;
    rs.x = rsqrtf(Bv.x * inv - mu.x * mu.x + 1e-5f);
    rs.y = rsqrtf(Bv.y * inv - mu.y * mu.y + 1e-5f);
    rs.z = rsqrtf(Bv.z * inv - mu.z * mu.z + 1e-5f);
    rs.w = rsqrtf(Bv.w * inv - mu.w * mu.w + 1e-5f);

    const float4* spv  = (const float4*)(sp  + (size_t)b * CDIM * SDIM + s0) + lane;
    nfloat4*      outv = (nfloat4*)     (out + (size_t)b * CDIM * SDIM + s0) + lane;

    const int rbeg = wave * 48;   // 48 rows per wave
    for (int r = rbeg; r < rbeg + 48; r += 4) {
        float4 v[4];
#pragma unroll
        for (int k = 0; k < 4; ++k)
            v[k] = spv[(size_t)(c_base + r + k) * (SDIM / 4)];
#pragma unroll
        for (int k = 0; k < 4; ++k) {
            float p  = s_p[r + k];
            float g  = s_g[r + k];
            float be = s_b[r + k];
            nfloat4 y;
            y.x = (v[k].x + p - mu.x) * rs.x * g + be;
            y.y = (v[k].y + p - mu.y) * rs.y * g + be;
            y.z = (v[k].z + p - mu.z) * rs.z * g + be;
            y.w = (v[k].w + p - mu.w) * rs.w * g + be;
            __builtin_nontemporal_store(y, &outv[(size_t)(c_base + r + k) * (SDIM / 4)]);
        }
    }
}

extern "C" void kernel_launch(void* const* d_in, const int* in_sizes, int n_in,
                              void* d_out, int out_size, void* d_ws, size_t ws_size,
                              hipStream_t stream) {
    const float* sp           = (const float*)d_in[0];
    const float* conditioning = (const float*)d_in[1];
    const float* w_cond       = (const float*)d_in[2];
    const float* b_cond       = (const float*)d_in[3];
    const float* in_proj_w    = (const float*)d_in[4];
    const float* in_proj_b    = (const float*)d_in[5];
    const float* attn_out_w   = (const float*)d_in[6];
    const float* attn_out_b   = (const float*)d_in[7];
    const float* w_out        = (const float*)d_in[8];
    const float* b_out        = (const float*)d_in[9];
    const float* ln_gamma     = (const float*)d_in[10];
    const float* ln_beta      = (const float*)d_in[11];
    float* out = (float*)d_out;
    float* ws  = (float*)d_ws;

    float* cond = ws;            // 16*768
    float* v    = ws + 12288;    // 16*768
    float* attn = ws + 24576;    // 16*768
    float* proj = ws + 36864;    // 16*768
    float* Ast  = ws + 49152;    // 16*4096
    float* Bst  = ws + 114688;   // 16*4096   (total ws: 180224 floats = 704KB)

    const int gemm_blocks = (16 * CDIM) / 4; // 4 waves/block, one wave per output
    small_gemm_kernel<<<gemm_blocks, 256, 0, stream>>>(
        conditioning, w_cond, b_cond, cond, CDIM, 1024);
    small_gemm_kernel<<<gemm_blocks, 256, 0, stream>>>(
        cond, in_proj_w + 2 * CDIM * CDIM, in_proj_b + 2 * CDIM, v, CDIM, CDIM);
    small_gemm_kernel<<<gemm_blocks, 256, 0, stream>>>(
        v, attn_out_w, attn_out_b, attn, CDIM, CDIM);
    small_gemm_kernel<<<gemm_blocks, 256, 0, stream>>>(
        attn, w_out, b_out, proj, CDIM, CDIM);

    ln_stats<<<dim3(SDIM / 128, 16), 256, 0, stream>>>(sp, proj, Ast, Bst);
    ln_norm<<<dim3(SDIM / 256, 16, 4), 256, 0, stream>>>(
        sp, proj, Ast, Bst, ln_gamma, ln_beta, out);
}

// Round 5
// 410.073 us; speedup vs baseline: 1.6751x; 1.0023x over previous
//
#include <hip/hip_runtime.h>

#define CDIM 768
#define SDIM 4096

typedef float nfloat2 __attribute__((ext_vector_type(2))); // native vec for nontemporal builtin

// out[b,c] = bias[c] + sum_k X[b,k] * W[c,k]   (one wave per output element)
__global__ __launch_bounds__(256) void small_gemm_kernel(
    const float* __restrict__ X, const float* __restrict__ W,
    const float* __restrict__ bias, float* __restrict__ out,
    int Cn, int K)
{
    int gid  = blockIdx.x * blockDim.x + threadIdx.x;
    int wid  = gid >> 6;
    int lane = threadIdx.x & 63;
    int total = 16 * Cn;
    if (wid >= total) return;
    int b = wid / Cn;
    int c = wid - b * Cn;
    const float* x = X + (size_t)b * K;
    const float* w = W + (size_t)c * K;
    float acc = 0.f;
    for (int k = lane * 4; k < K; k += 256) {
        float4 xv = *(const float4*)(x + k);
        float4 wv = *(const float4*)(w + k);
        acc += xv.x * wv.x + xv.y * wv.y + xv.z * wv.z + xv.w * wv.w;
    }
#pragma unroll
    for (int m = 32; m; m >>= 1) acc += __shfl_xor(acc, m, 64);
    if (lane == 0) out[wid] = acc + bias[c];
}

// Pass 1: partial A = sum_c (sp+p), B = sum_c (sp+p)^2 over a 384-c chunk.
// grid (SDIM/128, 16, 2): block = (b, 128-s span, half the c's) -> 1024 blocks
// (2x R4's 512; 50% occupancy). Wave w owns 96 c-rows; lane owns 2 consecutive
// s (float2): each wave-load = 512B contiguous. Partials packed as float4
// (A.x,B.x,A.y,B.y) per s-pair per z; pass 2 sums the two z-partials.
__global__ __launch_bounds__(256) void ln_stats(
    const float* __restrict__ sp, const float* __restrict__ proj,
    float4* __restrict__ AB)
{
    __shared__ float s_proj[CDIM / 2];
    __shared__ float2 redA[4][64];
    __shared__ float2 redB[4][64];
    const int b  = blockIdx.y;
    const int s0 = blockIdx.x * 128;
    const int z  = blockIdx.z;
    const int t  = threadIdx.x;
    for (int i = t; i < CDIM / 2; i += 256) s_proj[i] = proj[b * CDIM + z * (CDIM / 2) + i];
    __syncthreads();

    const int lane = t & 63;
    const int wave = t >> 6;
    const float2* base = (const float2*)(sp + (size_t)b * CDIM * SDIM
                                            + (size_t)z * (CDIM / 2) * SDIM + s0) + lane;

    float2 A = make_float2(0.f, 0.f), B = make_float2(0.f, 0.f);
    const int lc0 = wave * 96;            // 96 local c-rows per wave
    for (int lc = lc0; lc < lc0 + 96; lc += 8) {
        float2 v[8];
#pragma unroll
        for (int k = 0; k < 8; ++k) v[k] = base[(size_t)(lc + k) * (SDIM / 2)];
#pragma unroll
        for (int k = 0; k < 8; ++k) {
            float p  = s_proj[lc + k];
            float ax = v[k].x + p, ay = v[k].y + p;
            A.x += ax;      A.y += ay;
            B.x += ax * ax; B.y += ay * ay;
        }
    }
    redA[wave][lane] = A;
    redB[wave][lane] = B;
    __syncthreads();

    if (t < 64) {
        float2 a = redA[0][t], bb = redB[0][t];
#pragma unroll
        for (int w = 1; w < 4; ++w) {
            a.x  += redA[w][t].x;  a.y  += redA[w][t].y;
            bb.x += redB[w][t].x;  bb.y += redB[w][t].y;
        }
        // one float4 per s-pair: (A_even, B_even, A_odd, B_odd)
        AB[((size_t)z * 16 + b) * (SDIM / 2) + s0 / 2 + t] =
            make_float4(a.x, bb.x, a.y, bb.y);
    }
}

// Pass 2: normalize + write. grid (SDIM/128, 16, 4) = 2048 blocks -> 8
// blocks/CU, 100% occupancy. Lane owns 2 consecutive s; mu/rs in registers.
// Per row: 512B contiguous wave-load of sp (should hit L3, warmed by pass 1),
// FMA, 512B contiguous nontemporal wave-store (NT keeps sp resident in L3).
__global__ __launch_bounds__(256) void ln_norm(
    const float* __restrict__ sp, const float* __restrict__ proj,
    const float4* __restrict__ AB,
    const float* __restrict__ gamma, const float* __restrict__ beta,
    float* __restrict__ out)
{
    __shared__ float s_p[CDIM / 4], s_g[CDIM / 4], s_b[CDIM / 4];
    const int b      = blockIdx.y;
    const int s0     = blockIdx.x * 128;
    const int c_base = blockIdx.z * (CDIM / 4);   // 192 c's per block
    const int t      = threadIdx.x;
    if (t < CDIM / 4) {
        s_p[t] = proj[b * CDIM + c_base + t];
        s_g[t] = gamma[c_base + t];
        s_b[t] = beta[c_base + t];
    }
    __syncthreads();

    const int lane = t & 63;
    const int wave = t >> 6;

    float4 f0 = AB[((size_t)0 * 16 + b) * (SDIM / 2) + s0 / 2 + lane];
    float4 f1 = AB[((size_t)1 * 16 + b) * (SDIM / 2) + s0 / 2 + lane];
    const float inv = 1.f / CDIM;
    float2 mu, rs;
    mu.x = (f0.x + f1.x) * inv;
    mu.y = (f0.z + f1.z) * inv;
    rs.x = rsqrtf((f0.y + f1.y) * inv - mu.x * mu.x + 1e-5f);
    rs.y = rsqrtf((f0.w + f1.w) * inv - mu.y * mu.y + 1e-5f);

    const float2* spv  = (const float2*)(sp  + (size_t)b * CDIM * SDIM
                                             + (size_t)c_base * SDIM + s0) + lane;
    nfloat2*      outv = (nfloat2*)     (out + (size_t)b * CDIM * SDIM
                                             + (size_t)c_base * SDIM + s0) + lane;

    const int rbeg = wave * 48;   // 48 rows per wave
    for (int r = rbeg; r < rbeg + 48; r += 8) {
        float2 v[8];
#pragma unroll
        for (int k = 0; k < 8; ++k)
            v[k] = spv[(size_t)(r + k) * (SDIM / 2)];
#pragma unroll
        for (int k = 0; k < 8; ++k) {
            float p  = s_p[r + k];
            float g  = s_g[r + k];
            float be = s_b[r + k];
            float gx = rs.x * g, gy = rs.y * g;
            nfloat2 y;
            y.x = (v[k].x + p - mu.x) * gx + be;
            y.y = (v[k].y + p - mu.y) * gy + be;
            __builtin_nontemporal_store(y, &outv[(size_t)(r + k) * (SDIM / 2)]);
        }
    }
}

extern "C" void kernel_launch(void* const* d_in, const int* in_sizes, int n_in,
                              void* d_out, int out_size, void* d_ws, size_t ws_size,
                              hipStream_t stream) {
    const float* sp           = (const float*)d_in[0];
    const float* conditioning = (const float*)d_in[1];
    const float* w_cond       = (const float*)d_in[2];
    const float* b_cond       = (const float*)d_in[3];
    const float* in_proj_w    = (const float*)d_in[4];
    const float* in_proj_b    = (const float*)d_in[5];
    const float* attn_out_w   = (const float*)d_in[6];
    const float* attn_out_b   = (const float*)d_in[7];
    const float* w_out        = (const float*)d_in[8];
    const float* b_out        = (const float*)d_in[9];
    const float* ln_gamma     = (const float*)d_in[10];
    const float* ln_beta      = (const float*)d_in[11];
    float* out = (float*)d_out;
    float* ws  = (float*)d_ws;

    float* cond = ws;            // 16*768
    float* v    = ws + 12288;    // 16*768
    float* attn = ws + 24576;    // 16*768
    float* proj = ws + 36864;    // 16*768
    float4* AB  = (float4*)(ws + 49152);  // 2*16*2048 float4 = 1MB (ws total ~1.2MB)

    const int gemm_blocks = (16 * CDIM) / 4; // 4 waves/block, one wave per output
    small_gemm_kernel<<<gemm_blocks, 256, 0, stream>>>(
        conditioning, w_cond, b_cond, cond, CDIM, 1024);
    small_gemm_kernel<<<gemm_blocks, 256, 0, stream>>>(
        cond, in_proj_w + 2 * CDIM * CDIM, in_proj_b + 2 * CDIM, v, CDIM, CDIM);
    small_gemm_kernel<<<gemm_blocks, 256, 0, stream>>>(
        v, attn_out_w, attn_out_b, attn, CDIM, CDIM);
    small_gemm_kernel<<<gemm_blocks, 256, 0, stream>>>(
        attn, w_out, b_out, proj, CDIM, CDIM);

    ln_stats<<<dim3(SDIM / 128, 16, 2), 256, 0, stream>>>(sp, proj, AB);
    ln_norm<<<dim3(SDIM / 128, 16, 4), 256, 0, stream>>>(
        sp, proj, AB, ln_gamma, ln_beta, out);
}